// Round 13
// baseline (291.744 us; speedup 1.0000x reference)
//
#include <hip/hip_runtime.h>
#include <math.h>

#define NN 32000
#define FIN 128
#define HC 256      // HEADS*CH
#define NH 4        // heads
#define HIDD 512
#define BB 64       // batch
#define ZD 64
#define NSPLIT 125  // big-gemm K splits
#define KBCH 1024   // K rows per split (125*1024 = 128000)
#define BNB 128     // big-gemm N per block (4 n-groups)

typedef __bf16 bf16x8 __attribute__((ext_vector_type(8)));
typedef float f32x4 __attribute__((ext_vector_type(4)));
typedef unsigned int uint;

__device__ inline float lrelu(float x){ return x > 0.f ? x : 0.2f*x; }
__device__ inline unsigned short f2b(float f){           // fp32 -> bf16 RNE
  uint u = __float_as_uint(f);
  return (unsigned short)((u + 0x7FFFu + ((u >> 16) & 1u)) >> 16);
}
__device__ inline float b2f(unsigned short b){ return __uint_as_float(((uint)b) << 16); }
__device__ inline float blo(uint v){ return __uint_as_float(v << 16); }
__device__ inline float bhi(uint v){ return __uint_as_float(v & 0xffff0000u); }
__device__ inline uint cvtpk(float lo, float hi){        // packed bf16 RNE, 1 instr
  uint pk;
  asm("v_cvt_pk_bf16_f32 %0, %1, %2" : "=v"(pk) : "v"(lo), "v"(hi));
  return pk;
}

// ---- prep0: edge dtype detect (block 0, wave 0) + zero counts (grid-stride) ----
__global__ void k_prep0(const void* ei, int* flag, int* counts){
  int b = blockIdx.x, t = threadIdx.x;
  if (b == 0 && t < 64){
    int v = ((const int*)ei)[2*t + 1];
    unsigned long long bal = __ballot(v == 0);
    if (t == 0) *flag = (bal == ~0ULL) ? 1 : 0;
  }
  for (int i = b*256 + t; i < NN; i += gridDim.x*256) counts[i] = 0;
}

// ---- prep1: x->bf16 vectorized (blocks 0..3999, 4 elems/thread),
//             W1/W2 transpose-cvt (4000..4511), dst histogram (4512..). ----
__global__ void k_prep1(const float* __restrict__ x, unsigned short* __restrict__ xb,
                        const float* __restrict__ W1, unsigned short* __restrict__ Wt1,
                        const float* __restrict__ W2, unsigned short* __restrict__ Wt2,
                        const void* ei, const int* __restrict__ flag,
                        int* __restrict__ counts, int E){
  int b = blockIdx.x, t = threadIdx.x;
  if (b < 4000){
    int i = b*1024 + t*4;
    float4 v = *(const float4*)&x[i];
    uint p0 = cvtpk(v.x, v.y), p1 = cvtpk(v.z, v.w);
    uint2 o; o.x = p0; o.y = p1;
    *(uint2*)&xb[i] = o;
  } else if (b < 4512){
    int bb = b - 4000;
    int n = bb & 255, which = bb >> 8;
    if (which == 0){ if (t < FIN) Wt1[n*FIN + t] = f2b(W1[t*HC + n]); }
    else           { Wt2[n*HC + t] = f2b(W2[t*HC + n]); }
  } else {
    int i = (b - 4512)*256 + t;
    if (i < E){
      int d = *flag ? (int)((const long long*)ei)[E + i] : ((const int*)ei)[E + i];
      atomicAdd(&counts[d], 1);
    }
  }
}

// ---- scanA: per-block sums of 256 contiguous counts ----
__global__ __launch_bounds__(256) void k_scanA(const int* __restrict__ counts,
                                               int* __restrict__ bsum){
  __shared__ int red[256];
  int b = blockIdx.x, t = threadIdx.x;
  red[t] = counts[b*256 + t];
  __syncthreads();
  #pragma unroll
  for (int o = 128; o; o >>= 1){
    if (t < o) red[t] += red[t + o];
    __syncthreads();
  }
  if (t == 0) bsum[b] = red[0];
}

// ---- scanC: block computes its own base (sum of bsum[0..b)) + local scan ----
__global__ __launch_bounds__(256) void k_scanC(const int* __restrict__ counts,
    const int* __restrict__ bsum, int* __restrict__ offs, int* __restrict__ cursor){
  __shared__ int s[256];
  int b = blockIdx.x, t = threadIdx.x;
  int bv = (t < b) ? bsum[t] : 0;       // b <= 124 < 256
  s[t] = bv;
  __syncthreads();
  #pragma unroll
  for (int o = 128; o; o >>= 1){
    if (t < o) s[t] += s[t + o];
    __syncthreads();
  }
  int base = s[0];
  __syncthreads();
  int v = counts[b*256 + t];
  s[t] = v;
  __syncthreads();
  for (int o = 1; o < 256; o <<= 1){
    int u = (t >= o) ? s[t - o] : 0;
    __syncthreads();
    s[t] += u;
    __syncthreads();
  }
  int excl = s[t] - v + base;
  offs[b*256 + t] = excl;
  cursor[b*256 + t] = excl;
  if (b == (NN/256 - 1) && t == 255) offs[NN] = excl + v;
}

// ---- node GEMM body (MFMA bf16, dbuf LDS — proven): out[64,256] tile + att dots ----
__device__ __forceinline__ void gemm_n_body(const unsigned short* __restrict__ A,
    const unsigned short* __restrict__ Wt, int K,
    const float* __restrict__ ws, const float* __restrict__ wd,
    unsigned short* __restrict__ out, float* __restrict__ a_s, float* __restrict__ a_d,
    int m0){
  __shared__ unsigned short As[2][64][40];
  __shared__ unsigned short Bs[2][256][40];
  int t = threadIdx.x;
  int w = t >> 6, lane = t & 63, l15 = lane & 15, l16 = lane >> 4;
  int arow = t >> 2, ako = (t & 3) * 8;
  const unsigned short* aptr = A + (size_t)(m0 + arow)*K + ako;
  const unsigned short* bptr = Wt + (size_t)t*K;
  f32x4 acc[16];
  #pragma unroll
  for (int c = 0; c < 16; c++) acc[c] = (f32x4){0.f,0.f,0.f,0.f};

  uint4 a4 = *(const uint4*)aptr;
  uint4 b4[4];
  #pragma unroll
  for (int p = 0; p < 4; p++) b4[p] = *(const uint4*)(bptr + p*8);

  int pp = 0;
  for (int k0 = 0; k0 < K; k0 += 32){
    *(uint4*)&As[pp][arow][ako] = a4;
    #pragma unroll
    for (int p = 0; p < 4; p++) *(uint4*)&Bs[pp][t][p*8] = b4[p];
    __syncthreads();
    if (k0 + 32 < K){
      a4 = *(const uint4*)(aptr + k0 + 32);
      #pragma unroll
      for (int p = 0; p < 4; p++) b4[p] = *(const uint4*)(bptr + k0 + 32 + p*8);
    }
    bf16x8 af = *(const bf16x8*)&As[pp][w*16 + l15][l16*8];
    #pragma unroll
    for (int c = 0; c < 16; c++){
      bf16x8 bfr = *(const bf16x8*)&Bs[pp][c*16 + l15][l16*8];
      acc[c] = __builtin_amdgcn_mfma_f32_16x16x32_bf16(af, bfr, acc[c], 0, 0, 0);
    }
    pp ^= 1;
  }

  #pragma unroll
  for (int r = 0; r < 4; r++){
    int row = m0 + w*16 + l16*4 + r;
    float hs[NH] = {0,0,0,0}, hd[NH] = {0,0,0,0};
    #pragma unroll
    for (int c = 0; c < 16; c++){
      float v = acc[c][r];
      int colc = c*16 + l15;
      out[(size_t)row*HC + colc] = f2b(v);
      hs[c>>2] += v * ws[colc];
      hd[c>>2] += v * wd[colc];
    }
    #pragma unroll
    for (int h = 0; h < NH; h++){
      float s = hs[h], d = hd[h];
      #pragma unroll
      for (int o = 1; o < 16; o <<= 1){ s += __shfl_xor(s, o); d += __shfl_xor(d, o); }
      if (l15 == h){ a_s[row*NH + h] = s; a_d[row*NH + h] = d; }
    }
  }
}

// layer-2 plain node GEMM
__global__ __launch_bounds__(256) void k_gemm_n(const unsigned short* __restrict__ A,
    const unsigned short* __restrict__ Wt, int K,
    const float* __restrict__ ws, const float* __restrict__ wd,
    unsigned short* __restrict__ out, float* __restrict__ a_s, float* __restrict__ a_d){
  gemm_n_body(A, Wt, K, ws, wd, out, a_s, a_d, blockIdx.x * 64);
}

// layer-1 node GEMM fused with CSR fill (independent work, overlapped):
// blocks [0,500) = gemm tiles; blocks [500, 500+nfill) = fill.
__global__ __launch_bounds__(256) void k_gemm1f(const unsigned short* __restrict__ A,
    const unsigned short* __restrict__ Wt, int K,
    const float* __restrict__ ws, const float* __restrict__ wd,
    unsigned short* __restrict__ out, float* __restrict__ a_s, float* __restrict__ a_d,
    const void* ei, const int* __restrict__ flag,
    int* __restrict__ cursor, int* __restrict__ col, int E){
  if (blockIdx.x < NN/64){
    gemm_n_body(A, Wt, K, ws, wd, out, a_s, a_d, blockIdx.x * 64);
  } else {
    int i = (blockIdx.x - NN/64)*256 + threadIdx.x;
    if (i < E){
      int s, d;
      if (*flag){ s = (int)((const long long*)ei)[i]; d = (int)((const long long*)ei)[E + i]; }
      else      { s = ((const int*)ei)[i];            d = ((const int*)ei)[E + i]; }
      int pos = atomicAdd(&cursor[d], 1);
      col[pos] = s;
    }
  }
}

// ---- fused GAT softmax + aggregation (proven): one wave per node,
// 4 edges/iteration; group g = lane>>4 owns edge, l16 owns 16 channels. ----
__global__ __launch_bounds__(256) void k_agg(const unsigned short* __restrict__ hp,
    const int* __restrict__ col, const int* __restrict__ offs,
    const float* __restrict__ a_s, const float* __restrict__ a_d,
    const float* __restrict__ bias, unsigned short* __restrict__ outb){
  int n = blockIdx.x*4 + (threadIdx.x >> 6);
  int lane = threadIdx.x & 63;
  int g = lane >> 4, l16 = lane & 15;
  int h = l16 >> 2;
  int c0 = l16 * 16;
  int b0 = offs[n], b1 = offs[n+1];
  float adh = a_d[n*NH + h];
  float pself = expf(lrelu(a_s[n*NH + h] + adh));
  float den = 0.f;
  float ac[16];
  #pragma unroll
  for (int j = 0; j < 16; j++) ac[j] = 0.f;
  #pragma unroll 2
  for (int i = b0 + g; i < b1; i += 4){
    int s = col[i];
    float p = expf(lrelu(a_s[s*NH + h] + adh));
    den += p;
    uint4 v0 = *(const uint4*)&hp[(size_t)s*HC + c0];
    uint4 v1 = *(const uint4*)&hp[(size_t)s*HC + c0 + 8];
    ac[0] = fmaf(p, blo(v0.x), ac[0]);   ac[1] = fmaf(p, bhi(v0.x), ac[1]);
    ac[2] = fmaf(p, blo(v0.y), ac[2]);   ac[3] = fmaf(p, bhi(v0.y), ac[3]);
    ac[4] = fmaf(p, blo(v0.z), ac[4]);   ac[5] = fmaf(p, bhi(v0.z), ac[5]);
    ac[6] = fmaf(p, blo(v0.w), ac[6]);   ac[7] = fmaf(p, bhi(v0.w), ac[7]);
    ac[8] = fmaf(p, blo(v1.x), ac[8]);   ac[9] = fmaf(p, bhi(v1.x), ac[9]);
    ac[10]= fmaf(p, blo(v1.y), ac[10]);  ac[11]= fmaf(p, bhi(v1.y), ac[11]);
    ac[12]= fmaf(p, blo(v1.z), ac[12]);  ac[13]= fmaf(p, bhi(v1.z), ac[13]);
    ac[14]= fmaf(p, blo(v1.w), ac[14]);  ac[15]= fmaf(p, bhi(v1.w), ac[15]);
  }
  den += __shfl_xor(den, 16);  den += __shfl_xor(den, 32);
  #pragma unroll
  for (int j = 0; j < 16; j++){
    ac[j] += __shfl_xor(ac[j], 16);
    ac[j] += __shfl_xor(ac[j], 32);
  }
  den += pself;
  float r = 1.f / den;
  if (g == 0){
    uint4 hv0 = *(const uint4*)&hp[(size_t)n*HC + c0];
    uint4 hv1 = *(const uint4*)&hp[(size_t)n*HC + c0 + 8];
    float hvf[16] = {blo(hv0.x),bhi(hv0.x),blo(hv0.y),bhi(hv0.y),
                     blo(hv0.z),bhi(hv0.z),blo(hv0.w),bhi(hv0.w),
                     blo(hv1.x),bhi(hv1.x),blo(hv1.y),bhi(hv1.y),
                     blo(hv1.z),bhi(hv1.z),blo(hv1.w),bhi(hv1.w)};
    uint ov[8];
    #pragma unroll
    for (int j = 0; j < 8; j++){
      float e0 = fmaxf((pself*hvf[2*j]   + ac[2*j]  )*r + bias[c0+2*j],   0.f);
      float e1 = fmaxf((pself*hvf[2*j+1] + ac[2*j+1])*r + bias[c0+2*j+1], 0.f);
      ov[j] = ((uint)f2b(e1) << 16) | (uint)f2b(e0);
    }
    *(uint4*)&outb[(size_t)n*HC + c0]     = *(uint4*)&ov[0];
    *(uint4*)&outb[(size_t)n*HC + c0 + 8] = *(uint4*)&ov[4];
  }
}

// ---- big GEMM (MFMA bf16), dbuf LDS, cvt_pk pack, ATOMIC accumulate into y.
// be is dropped: BatchNorm subtracts the batch mean, which contains be exactly. ----
__global__ __launch_bounds__(256) void k_gemm_big(const unsigned short* __restrict__ xg,
    const float* __restrict__ We, float* __restrict__ y){
  __shared__ unsigned short As[2][64][40];
  __shared__ unsigned short Bs[2][BNB][40];
  int n0 = blockIdx.x * BNB;
  int kc = blockIdx.y;
  int kbase = kc * KBCH;
  int t = threadIdx.x, w = t >> 6, lane = t & 63, l15 = lane & 15, l16 = lane >> 4;
  int cc = t & (BNB-1);
  int khalf = t >> 7;
  int arow = t >> 2, ako = (t & 3) * 8;
  const float* bptr = We + (size_t)(kbase + khalf*16)*HIDD + n0 + cc;
  const unsigned short* aptr = xg + (size_t)arow*128000 + kbase + ako;
  f32x4 acc[8];
  #pragma unroll
  for (int c = 0; c < 8; c++) acc[c] = (f32x4){0.f,0.f,0.f,0.f};

  float rv[16]; uint4 a4;
  #pragma unroll
  for (int mm = 0; mm < 16; mm++) rv[mm] = bptr[(size_t)mm*HIDD];
  a4 = *(const uint4*)aptr;

  int p = 0;
  for (int ks = 0; ks < KBCH; ks += 32){
    *(uint4*)&As[p][arow][ako] = a4;
    #pragma unroll
    for (int j = 0; j < 8; j++)
      *(uint*)&Bs[p][cc][khalf*16 + 2*j] = cvtpk(rv[2*j], rv[2*j+1]);
    __syncthreads();
    if (ks + 32 < KBCH){
      const float* bp2 = bptr + (size_t)(ks + 32)*HIDD;
      #pragma unroll
      for (int mm = 0; mm < 16; mm++) rv[mm] = bp2[(size_t)mm*HIDD];
      a4 = *(const uint4*)(aptr + ks + 32);
    }
    bf16x8 af = *(const bf16x8*)&As[p][w*16 + l15][l16*8];
    #pragma unroll
    for (int c = 0; c < 8; c++){
      bf16x8 bfr = *(const bf16x8*)&Bs[p][c*16 + l15][l16*8];
      acc[c] = __builtin_amdgcn_mfma_f32_16x16x32_bf16(af, bfr, acc[c], 0, 0, 0);
    }
    p ^= 1;
  }
  #pragma unroll
  for (int r = 0; r < 4; r++){
    int row = w*16 + l16*4 + r;
    #pragma unroll
    for (int c = 0; c < 8; c++)
      atomicAdd(&y[row*HIDD + n0 + c*16 + l15], acc[c][r]);
  }
}

// BatchNorm over batch axis
__global__ __launch_bounds__(64) void k_bn(const float* __restrict__ y,
    float* __restrict__ ybn){
  int colb = blockIdx.x, r = threadIdx.x;
  float v = y[(size_t)r*HIDD + colb];
  float s = v, s2 = v*v;
  #pragma unroll
  for (int o = 32; o; o >>= 1){ s += __shfl_down(s, o); s2 += __shfl_down(s2, o); }
  s = __shfl(s, 0); s2 = __shfl(s2, 0);
  float mean = s * (1.f/BB);
  float var = s2 * (1.f/BB) - mean*mean;
  ybn[(size_t)r*HIDD + colb] = (v - mean) * rsqrtf(var + 1e-3f);
}

// LayerNorm + relu + both head GEMMs fused. grid BB, 512 threads.
__global__ __launch_bounds__(512) void k_lnheads(const float* __restrict__ ybn,
    const float* __restrict__ Wmu, const float* __restrict__ bmu,
    const float* __restrict__ Wvar, const float* __restrict__ bvar,
    float* __restrict__ out){
  __shared__ float ssum[8], ssq[8];
  __shared__ float yrow[HIDD];
  int row = blockIdx.x, t = threadIdx.x;
  float v = ybn[(size_t)row*HIDD + t];
  float s = v, s2 = v*v;
  #pragma unroll
  for (int o = 32; o; o >>= 1){ s += __shfl_down(s, o); s2 += __shfl_down(s2, o); }
  if ((t & 63) == 0){ ssum[t>>6] = s; ssq[t>>6] = s2; }
  __syncthreads();
  if (t == 0){
    float S = 0, S2 = 0;
    for (int i = 0; i < 8; i++){ S += ssum[i]; S2 += ssq[i]; }
    ssum[0] = S; ssq[0] = S2;
  }
  __syncthreads();
  float mean = ssum[0] * (1.f/HIDD);
  float var = ssq[0] * (1.f/HIDD) - mean*mean;
  yrow[t] = fmaxf((v - mean) * rsqrtf(var + 1e-5f), 0.f);
  __syncthreads();
  int o = t >> 2, kq = t & 3;
  const float* Wc = (o < ZD) ? Wmu : Wvar;
  int j = (o < ZD) ? o : o - ZD;
  float acc = 0.f;
  #pragma unroll 4
  for (int k = kq*128; k < kq*128 + 128; k++)
    acc = fmaf(yrow[k], Wc[(size_t)k*ZD + j], acc);
  acc += __shfl_down(acc, 1);
  acc += __shfl_down(acc, 2);
  if (kq == 0){
    if (o < ZD) out[row*ZD + o] = acc + bmu[o];
    else        out[BB*ZD + row*ZD + j] = expf(acc + bvar[j]) + 1e-4f;
  }
}

extern "C" void kernel_launch(void* const* d_in, const int* in_sizes, int n_in,
                              void* d_out, int out_size, void* d_ws, size_t ws_size,
                              hipStream_t stream){
  const float* x    = (const float*)d_in[0];
  const float* W1   = (const float*)d_in[1];
  const float* as1  = (const float*)d_in[2];
  const float* ad1  = (const float*)d_in[3];
  const float* b1   = (const float*)d_in[4];
  const float* W2   = (const float*)d_in[5];
  const float* as2  = (const float*)d_in[6];
  const float* ad2  = (const float*)d_in[7];
  const float* b2   = (const float*)d_in[8];
  const float* We   = (const float*)d_in[9];
  const float* Wmu  = (const float*)d_in[11];
  const float* bmu  = (const float*)d_in[12];
  const float* Wvar = (const float*)d_in[13];
  const float* bvar = (const float*)d_in[14];
  const void*  ei   = d_in[15];
  int E = in_sizes[15] / 2;

  char* w = (char*)d_ws;
  auto alloc = [&](size_t bytes)->void*{
    void* p = (void*)w; w += (bytes + 255) & ~(size_t)255; return p;
  };
  unsigned short* gb   = (unsigned short*)alloc((size_t)NN*HC*2);
  unsigned short* ab   = (unsigned short*)alloc((size_t)NN*HC*2);
  unsigned short* xb   = (unsigned short*)alloc((size_t)NN*FIN*2);
  unsigned short* Wt1  = (unsigned short*)alloc((size_t)HC*FIN*2);
  unsigned short* Wt2  = (unsigned short*)alloc((size_t)HC*HC*2);
  float*    a_s    = (float*)alloc((size_t)NN*NH*4);
  float*    a_d    = (float*)alloc((size_t)NN*NH*4);
  int*      counts = (int*)alloc((size_t)NN*4);
  int*      offs   = (int*)alloc((size_t)(NN+1)*4);
  int*      cursor = (int*)alloc((size_t)NN*4);
  int*      col    = (int*)alloc((size_t)E*4);
  int*      bsum   = (int*)alloc((size_t)256*4);
  int*      flag   = (int*)alloc(256);
  float*    y      = (float*)alloc((size_t)BB*HIDD*4);
  float*    ybn    = (float*)alloc((size_t)BB*HIDD*4);

  int nfill = (E + 255)/256;

  // prep: detect + zero counts; then cvt(vec4) + cvtT + hist in one launch
  k_prep0<<<125, 256, 0, stream>>>(ei, flag, counts);
  k_prep1<<<4512 + nfill, 256, 0, stream>>>(x, xb, W1, Wt1, W2, Wt2,
                                            ei, flag, counts, E);
  // 2-phase coalesced scan (scanB folded into scanC)
  k_scanA<<<NN/256, 256, 0, stream>>>(counts, bsum);
  k_scanC<<<NN/256, 256, 0, stream>>>(counts, bsum, offs, cursor);

  // GAT layer 1 (gemm fused with CSR fill — independent, overlapped)
  k_gemm1f<<<NN/64 + nfill, 256, 0, stream>>>(xb, Wt1, FIN, as1, ad1, gb, a_s, a_d,
                                              ei, flag, cursor, col, E);
  k_agg<<<NN/4, 256, 0, stream>>>(gb, col, offs, a_s, a_d, b1, ab);

  // GAT layer 2
  k_gemm_n<<<NN/64, 256, 0, stream>>>(ab, Wt2, HC, as2, ad2, gb, a_s, a_d);
  k_agg<<<NN/4, 256, 0, stream>>>(gb, col, offs, a_s, a_d, b2, ab);

  // encoder head: y zeroed, gemm_big atomically accumulates (be cancels in BN)
  hipMemsetAsync(y, 0, (size_t)BB*HIDD*4, stream);
  k_gemm_big<<<dim3(HIDD/BNB, NSPLIT), 256, 0, stream>>>(ab, We, y);
  k_bn<<<HIDD, 64, 0, stream>>>(y, ybn);
  k_lnheads<<<BB, 512, 0, stream>>>(ybn, Wmu, bmu, Wvar, bvar, (float*)d_out);
}

// Round 16
// 287.871 us; speedup vs baseline: 1.0135x; 1.0135x over previous
//
#include <hip/hip_runtime.h>
#include <math.h>

#define NN 32000
#define FIN 128
#define HC 256      // HEADS*CH
#define NH 4        // heads
#define HIDD 512
#define BB 64       // batch
#define ZD 64
#define NSPLIT 125  // big-gemm K splits
#define KBCH 1024   // K rows per split (125*1024 = 128000)
#define BNB 128     // big-gemm N per block (4 n-groups)

typedef __bf16 bf16x8 __attribute__((ext_vector_type(8)));
typedef float f32x4 __attribute__((ext_vector_type(4)));
typedef unsigned int uint;

__device__ inline float lrelu(float x){ return x > 0.f ? x : 0.2f*x; }
__device__ inline unsigned short f2b(float f){           // fp32 -> bf16 RNE
  uint u = __float_as_uint(f);
  return (unsigned short)((u + 0x7FFFu + ((u >> 16) & 1u)) >> 16);
}
__device__ inline float b2f(unsigned short b){ return __uint_as_float(((uint)b) << 16); }
__device__ inline float blo(uint v){ return __uint_as_float(v << 16); }
__device__ inline float bhi(uint v){ return __uint_as_float(v & 0xffff0000u); }
__device__ inline uint cvtpk(float lo, float hi){        // packed bf16 RNE, 1 instr
  uint pk;
  asm("v_cvt_pk_bf16_f32 %0, %1, %2" : "=v"(pk) : "v"(lo), "v"(hi));
  return pk;
}

// ---- prep0: edge dtype detect (block 0, wave 0) + zero counts (grid-stride) ----
__global__ void k_prep0(const void* ei, int* flag, int* counts){
  int b = blockIdx.x, t = threadIdx.x;
  if (b == 0 && t < 64){
    int v = ((const int*)ei)[2*t + 1];
    unsigned long long bal = __ballot(v == 0);
    if (t == 0) *flag = (bal == ~0ULL) ? 1 : 0;
  }
  for (int i = b*256 + t; i < NN; i += gridDim.x*256) counts[i] = 0;
}

// ---- prep1: x->bf16 vectorized (blocks 0..3999, 4 elems/thread),
//             W1/W2 transpose-cvt (4000..4511), dst histogram (4512..). ----
__global__ void k_prep1(const float* __restrict__ x, unsigned short* __restrict__ xb,
                        const float* __restrict__ W1, unsigned short* __restrict__ Wt1,
                        const float* __restrict__ W2, unsigned short* __restrict__ Wt2,
                        const void* ei, const int* __restrict__ flag,
                        int* __restrict__ counts, int E){
  int b = blockIdx.x, t = threadIdx.x;
  if (b < 4000){
    int i = b*1024 + t*4;
    float4 v = *(const float4*)&x[i];
    uint p0 = cvtpk(v.x, v.y), p1 = cvtpk(v.z, v.w);
    uint2 o; o.x = p0; o.y = p1;
    *(uint2*)&xb[i] = o;
  } else if (b < 4512){
    int bb = b - 4000;
    int n = bb & 255, which = bb >> 8;
    if (which == 0){ if (t < FIN) Wt1[n*FIN + t] = f2b(W1[t*HC + n]); }
    else           { Wt2[n*HC + t] = f2b(W2[t*HC + n]); }
  } else {
    int i = (b - 4512)*256 + t;
    if (i < E){
      int d = *flag ? (int)((const long long*)ei)[E + i] : ((const int*)ei)[E + i];
      atomicAdd(&counts[d], 1);
    }
  }
}

// ---- coalesced 3-phase scan (proven round-11) ----
__global__ __launch_bounds__(256) void k_scanA(const int* __restrict__ counts,
                                               int* __restrict__ bsum){
  __shared__ int red[256];
  int b = blockIdx.x, t = threadIdx.x;
  red[t] = counts[b*256 + t];
  __syncthreads();
  #pragma unroll
  for (int o = 128; o; o >>= 1){
    if (t < o) red[t] += red[t + o];
    __syncthreads();
  }
  if (t == 0) bsum[b] = red[0];
}

__global__ __launch_bounds__(128) void k_scanB(int* __restrict__ bsum, int nb){
  __shared__ int s[128];
  int t = threadIdx.x;
  int v = (t < nb) ? bsum[t] : 0;
  s[t] = v;
  __syncthreads();
  for (int o = 1; o < 128; o <<= 1){
    int u = (t >= o) ? s[t - o] : 0;
    __syncthreads();
    s[t] += u;
    __syncthreads();
  }
  if (t < nb) bsum[t] = s[t] - v;   // exclusive
}

__global__ __launch_bounds__(256) void k_scanC(const int* __restrict__ counts,
    const int* __restrict__ bsum, int* __restrict__ offs, int* __restrict__ cursor){
  __shared__ int s[256];
  int b = blockIdx.x, t = threadIdx.x;
  int v = counts[b*256 + t];
  s[t] = v;
  __syncthreads();
  for (int o = 1; o < 256; o <<= 1){
    int u = (t >= o) ? s[t - o] : 0;
    __syncthreads();
    s[t] += u;
    __syncthreads();
  }
  int excl = s[t] - v + bsum[b];
  offs[b*256 + t] = excl;
  cursor[b*256 + t] = excl;
  if (b == (NN/256 - 1) && t == 255) offs[NN] = excl + v;
}

// ---- CSR fill straight from raw edge_index ----
__global__ void k_fill(const void* ei, const int* __restrict__ flag,
                       int* __restrict__ cursor, int* __restrict__ col, int E){
  int i = blockIdx.x*256 + threadIdx.x;
  if (i < E){
    int s, d;
    if (*flag){ s = (int)((const long long*)ei)[i]; d = (int)((const long long*)ei)[E + i]; }
    else      { s = ((const int*)ei)[i];            d = ((const int*)ei)[E + i]; }
    int pos = atomicAdd(&cursor[d], 1);
    col[pos] = s;
  }
}

// ---- node GEMM (MFMA bf16), LDS double-buffered, 1 barrier/step (proven) ----
__global__ __launch_bounds__(256) void k_gemm_n(const unsigned short* __restrict__ A,
    const unsigned short* __restrict__ Wt, int K,
    const float* __restrict__ ws, const float* __restrict__ wd,
    unsigned short* __restrict__ out, float* __restrict__ a_s, float* __restrict__ a_d){
  __shared__ unsigned short As[2][64][40];
  __shared__ unsigned short Bs[2][256][40];
  int m0 = blockIdx.x * 64;
  int t = threadIdx.x;
  int w = t >> 6, lane = t & 63, l15 = lane & 15, l16 = lane >> 4;
  int arow = t >> 2, ako = (t & 3) * 8;
  const unsigned short* aptr = A + (size_t)(m0 + arow)*K + ako;
  const unsigned short* bptr = Wt + (size_t)t*K;
  f32x4 acc[16];
  #pragma unroll
  for (int c = 0; c < 16; c++) acc[c] = (f32x4){0.f,0.f,0.f,0.f};

  uint4 a4 = *(const uint4*)aptr;
  uint4 b4[4];
  #pragma unroll
  for (int p = 0; p < 4; p++) b4[p] = *(const uint4*)(bptr + p*8);

  int pp = 0;
  for (int k0 = 0; k0 < K; k0 += 32){
    *(uint4*)&As[pp][arow][ako] = a4;
    #pragma unroll
    for (int p = 0; p < 4; p++) *(uint4*)&Bs[pp][t][p*8] = b4[p];
    __syncthreads();
    if (k0 + 32 < K){
      a4 = *(const uint4*)(aptr + k0 + 32);
      #pragma unroll
      for (int p = 0; p < 4; p++) b4[p] = *(const uint4*)(bptr + k0 + 32 + p*8);
    }
    bf16x8 af = *(const bf16x8*)&As[pp][w*16 + l15][l16*8];
    #pragma unroll
    for (int c = 0; c < 16; c++){
      bf16x8 bfr = *(const bf16x8*)&Bs[pp][c*16 + l15][l16*8];
      acc[c] = __builtin_amdgcn_mfma_f32_16x16x32_bf16(af, bfr, acc[c], 0, 0, 0);
    }
    pp ^= 1;
  }

  // epilogue: store bf16 h, and per-head dots a_s = h·att_src, a_d = h·att_dst
  #pragma unroll
  for (int r = 0; r < 4; r++){
    int row = m0 + w*16 + l16*4 + r;
    float hs[NH] = {0,0,0,0}, hd[NH] = {0,0,0,0};
    #pragma unroll
    for (int c = 0; c < 16; c++){
      float v = acc[c][r];
      int colc = c*16 + l15;
      out[(size_t)row*HC + colc] = f2b(v);
      hs[c>>2] += v * ws[colc];
      hd[c>>2] += v * wd[colc];
    }
    #pragma unroll
    for (int h = 0; h < NH; h++){
      float s = hs[h], d = hd[h];
      #pragma unroll
      for (int o = 1; o < 16; o <<= 1){ s += __shfl_xor(s, o); d += __shfl_xor(d, o); }
      if (l15 == h){ a_s[row*NH + h] = s; a_d[row*NH + h] = d; }
    }
  }
}

// ---- fused GAT softmax + aggregation (proven): one wave per node,
// 4 edges/iteration; group g = lane>>4 owns edge, l16 owns 16 channels.
// No segment-max (shift-invariant, |e| small). ----
__global__ __launch_bounds__(256) void k_agg(const unsigned short* __restrict__ hp,
    const int* __restrict__ col, const int* __restrict__ offs,
    const float* __restrict__ a_s, const float* __restrict__ a_d,
    const float* __restrict__ bias, unsigned short* __restrict__ outb){
  int n = blockIdx.x*4 + (threadIdx.x >> 6);
  int lane = threadIdx.x & 63;
  int g = lane >> 4, l16 = lane & 15;
  int h = l16 >> 2;
  int c0 = l16 * 16;
  int b0 = offs[n], b1 = offs[n+1];
  float adh = a_d[n*NH + h];
  float pself = expf(lrelu(a_s[n*NH + h] + adh));
  float den = 0.f;
  float ac[16];
  #pragma unroll
  for (int j = 0; j < 16; j++) ac[j] = 0.f;
  #pragma unroll 2
  for (int i = b0 + g; i < b1; i += 4){
    int s = col[i];
    float p = expf(lrelu(a_s[s*NH + h] + adh));
    den += p;
    uint4 v0 = *(const uint4*)&hp[(size_t)s*HC + c0];
    uint4 v1 = *(const uint4*)&hp[(size_t)s*HC + c0 + 8];
    ac[0] = fmaf(p, blo(v0.x), ac[0]);   ac[1] = fmaf(p, bhi(v0.x), ac[1]);
    ac[2] = fmaf(p, blo(v0.y), ac[2]);   ac[3] = fmaf(p, bhi(v0.y), ac[3]);
    ac[4] = fmaf(p, blo(v0.z), ac[4]);   ac[5] = fmaf(p, bhi(v0.z), ac[5]);
    ac[6] = fmaf(p, blo(v0.w), ac[6]);   ac[7] = fmaf(p, bhi(v0.w), ac[7]);
    ac[8] = fmaf(p, blo(v1.x), ac[8]);   ac[9] = fmaf(p, bhi(v1.x), ac[9]);
    ac[10]= fmaf(p, blo(v1.y), ac[10]);  ac[11]= fmaf(p, bhi(v1.y), ac[11]);
    ac[12]= fmaf(p, blo(v1.z), ac[12]);  ac[13]= fmaf(p, bhi(v1.z), ac[13]);
    ac[14]= fmaf(p, blo(v1.w), ac[14]);  ac[15]= fmaf(p, bhi(v1.w), ac[15]);
  }
  den += __shfl_xor(den, 16);  den += __shfl_xor(den, 32);
  #pragma unroll
  for (int j = 0; j < 16; j++){
    ac[j] += __shfl_xor(ac[j], 16);
    ac[j] += __shfl_xor(ac[j], 32);
  }
  den += pself;
  float r = 1.f / den;
  if (g == 0){
    uint4 hv0 = *(const uint4*)&hp[(size_t)n*HC + c0];
    uint4 hv1 = *(const uint4*)&hp[(size_t)n*HC + c0 + 8];
    float hvf[16] = {blo(hv0.x),bhi(hv0.x),blo(hv0.y),bhi(hv0.y),
                     blo(hv0.z),bhi(hv0.z),blo(hv0.w),bhi(hv0.w),
                     blo(hv1.x),bhi(hv1.x),blo(hv1.y),bhi(hv1.y),
                     blo(hv1.z),bhi(hv1.z),blo(hv1.w),bhi(hv1.w)};
    uint ov[8];
    #pragma unroll
    for (int j = 0; j < 8; j++){
      float e0 = fmaxf((pself*hvf[2*j]   + ac[2*j]  )*r + bias[c0+2*j],   0.f);
      float e1 = fmaxf((pself*hvf[2*j+1] + ac[2*j+1])*r + bias[c0+2*j+1], 0.f);
      ov[j] = ((uint)f2b(e1) << 16) | (uint)f2b(e0);
    }
    *(uint4*)&outb[(size_t)n*HC + c0]     = *(uint4*)&ov[0];
    *(uint4*)&outb[(size_t)n*HC + c0 + 8] = *(uint4*)&ov[4];
  }
}

// ---- big GEMM (MFMA bf16), LDS double-buffered, 1 barrier/K-step, cvt_pk pack ----
__global__ __launch_bounds__(256) void k_gemm_big(const unsigned short* __restrict__ xg,
    const float* __restrict__ We, float* __restrict__ part){
  __shared__ unsigned short As[2][64][40];
  __shared__ unsigned short Bs[2][BNB][40];
  int n0 = blockIdx.x * BNB;
  int kc = blockIdx.y;
  int kbase = kc * KBCH;
  int t = threadIdx.x, w = t >> 6, lane = t & 63, l15 = lane & 15, l16 = lane >> 4;
  int cc = t & (BNB-1);
  int khalf = t >> 7;
  int arow = t >> 2, ako = (t & 3) * 8;
  const float* bptr = We + (size_t)(kbase + khalf*16)*HIDD + n0 + cc;
  const unsigned short* aptr = xg + (size_t)arow*128000 + kbase + ako;
  f32x4 acc[8];
  #pragma unroll
  for (int c = 0; c < 8; c++) acc[c] = (f32x4){0.f,0.f,0.f,0.f};

  float rv[16]; uint4 a4;
  #pragma unroll
  for (int mm = 0; mm < 16; mm++) rv[mm] = bptr[(size_t)mm*HIDD];
  a4 = *(const uint4*)aptr;

  int p = 0;
  for (int ks = 0; ks < KBCH; ks += 32){
    *(uint4*)&As[p][arow][ako] = a4;
    #pragma unroll
    for (int j = 0; j < 8; j++)
      *(uint*)&Bs[p][cc][khalf*16 + 2*j] = cvtpk(rv[2*j], rv[2*j+1]);
    __syncthreads();
    if (ks + 32 < KBCH){
      const float* bp2 = bptr + (size_t)(ks + 32)*HIDD;
      #pragma unroll
      for (int mm = 0; mm < 16; mm++) rv[mm] = bp2[(size_t)mm*HIDD];
      a4 = *(const uint4*)(aptr + ks + 32);
    }
    bf16x8 af = *(const bf16x8*)&As[p][w*16 + l15][l16*8];
    #pragma unroll
    for (int c = 0; c < 8; c++){
      bf16x8 bfr = *(const bf16x8*)&Bs[p][c*16 + l15][l16*8];
      acc[c] = __builtin_amdgcn_mfma_f32_16x16x32_bf16(af, bfr, acc[c], 0, 0, 0);
    }
    p ^= 1;
  }
  float* pbase = part + (size_t)kc*BB*HIDD;
  #pragma unroll
  for (int r = 0; r < 4; r++){
    int row = w*16 + l16*4 + r;
    #pragma unroll
    for (int c = 0; c < 8; c++)
      pbase[row*HIDD + n0 + c*16 + l15] = acc[c][r];
  }
}

// ---- reduce partials + bias ----
__global__ void k_reduce(const float* __restrict__ part, const float* __restrict__ be,
                         float* __restrict__ y){
  int o = blockIdx.x*256 + threadIdx.x;
  float s = 0.f;
  #pragma unroll 5
  for (int k = 0; k < NSPLIT; k++) s += part[(size_t)k*BB*HIDD + o];
  y[o] = s + be[o & (HIDD-1)];
}

// BatchNorm over batch axis
__global__ __launch_bounds__(64) void k_bn(const float* __restrict__ y,
    float* __restrict__ ybn){
  int colb = blockIdx.x, r = threadIdx.x;
  float v = y[(size_t)r*HIDD + colb];
  float s = v, s2 = v*v;
  #pragma unroll
  for (int o = 32; o; o >>= 1){ s += __shfl_down(s, o); s2 += __shfl_down(s2, o); }
  s = __shfl(s, 0); s2 = __shfl(s2, 0);
  float mean = s * (1.f/BB);
  float var = s2 * (1.f/BB) - mean*mean;
  ybn[(size_t)r*HIDD + colb] = (v - mean) * rsqrtf(var + 1e-3f);
}

// LayerNorm + relu + both head GEMMs fused. grid BB, 512 threads.
__global__ __launch_bounds__(512) void k_lnheads(const float* __restrict__ ybn,
    const float* __restrict__ Wmu, const float* __restrict__ bmu,
    const float* __restrict__ Wvar, const float* __restrict__ bvar,
    float* __restrict__ out){
  __shared__ float ssum[8], ssq[8];
  __shared__ float yrow[HIDD];
  int row = blockIdx.x, t = threadIdx.x;
  float v = ybn[(size_t)row*HIDD + t];
  float s = v, s2 = v*v;
  #pragma unroll
  for (int o = 32; o; o >>= 1){ s += __shfl_down(s, o); s2 += __shfl_down(s2, o); }
  if ((t & 63) == 0){ ssum[t>>6] = s; ssq[t>>6] = s2; }
  __syncthreads();
  if (t == 0){
    float S = 0, S2 = 0;
    for (int i = 0; i < 8; i++){ S += ssum[i]; S2 += ssq[i]; }
    ssum[0] = S; ssq[0] = S2;
  }
  __syncthreads();
  float mean = ssum[0] * (1.f/HIDD);
  float var = ssq[0] * (1.f/HIDD) - mean*mean;
  yrow[t] = fmaxf((v - mean) * rsqrtf(var + 1e-5f), 0.f);
  __syncthreads();
  int o = t >> 2, kq = t & 3;
  const float* Wc = (o < ZD) ? Wmu : Wvar;
  int j = (o < ZD) ? o : o - ZD;
  float acc = 0.f;
  #pragma unroll 4
  for (int k = kq*128; k < kq*128 + 128; k++)
    acc = fmaf(yrow[k], Wc[(size_t)k*ZD + j], acc);
  acc += __shfl_down(acc, 1);
  acc += __shfl_down(acc, 2);
  if (kq == 0){
    if (o < ZD) out[row*ZD + o] = acc + bmu[o];
    else        out[BB*ZD + row*ZD + j] = expf(acc + bvar[j]) + 1e-4f;
  }
}

extern "C" void kernel_launch(void* const* d_in, const int* in_sizes, int n_in,
                              void* d_out, int out_size, void* d_ws, size_t ws_size,
                              hipStream_t stream){
  const float* x    = (const float*)d_in[0];
  const float* W1   = (const float*)d_in[1];
  const float* as1  = (const float*)d_in[2];
  const float* ad1  = (const float*)d_in[3];
  const float* b1   = (const float*)d_in[4];
  const float* W2   = (const float*)d_in[5];
  const float* as2  = (const float*)d_in[6];
  const float* ad2  = (const float*)d_in[7];
  const float* b2   = (const float*)d_in[8];
  const float* We   = (const float*)d_in[9];
  const float* be   = (const float*)d_in[10];
  const float* Wmu  = (const float*)d_in[11];
  const float* bmu  = (const float*)d_in[12];
  const float* Wvar = (const float*)d_in[13];
  const float* bvar = (const float*)d_in[14];
  const void*  ei   = d_in[15];
  int E = in_sizes[15] / 2;

  char* w = (char*)d_ws;
  auto alloc = [&](size_t bytes)->void*{
    void* p = (void*)w; w += (bytes + 255) & ~(size_t)255; return p;
  };
  unsigned short* gb   = (unsigned short*)alloc((size_t)NN*HC*2);
  unsigned short* ab   = (unsigned short*)alloc((size_t)NN*HC*2);
  unsigned short* xb   = (unsigned short*)alloc((size_t)NN*FIN*2);
  unsigned short* Wt1  = (unsigned short*)alloc((size_t)HC*FIN*2);
  unsigned short* Wt2  = (unsigned short*)alloc((size_t)HC*HC*2);
  float*    a_s    = (float*)alloc((size_t)NN*NH*4);
  float*    a_d    = (float*)alloc((size_t)NN*NH*4);
  int*      counts = (int*)alloc((size_t)NN*4);
  int*      offs   = (int*)alloc((size_t)(NN+1)*4);
  int*      cursor = (int*)alloc((size_t)NN*4);
  int*      col    = (int*)alloc((size_t)E*4);
  int*      bsum   = (int*)alloc((size_t)256*4);
  int*      flag   = (int*)alloc(256);
  float*    part   = (float*)alloc((size_t)NSPLIT*BB*HIDD*4);
  float*    y      = (float*)alloc((size_t)BB*HIDD*4);
  float*    ybn    = (float*)alloc((size_t)BB*HIDD*4);

  // prep: detect + zero counts; then cvt(vec4) + cvtT + hist in one launch
  k_prep0<<<125, 256, 0, stream>>>(ei, flag, counts);
  k_prep1<<<4512 + (E + 255)/256, 256, 0, stream>>>(x, xb, W1, Wt1, W2, Wt2,
                                                    ei, flag, counts, E);
  // coalesced 3-phase scan
  k_scanA<<<NN/256, 256, 0, stream>>>(counts, bsum);
  k_scanB<<<1, 128, 0, stream>>>(bsum, NN/256);
  k_scanC<<<NN/256, 256, 0, stream>>>(counts, bsum, offs, cursor);
  k_fill<<<(E + 255)/256, 256, 0, stream>>>(ei, flag, cursor, col, E);

  // GAT layer 1
  k_gemm_n<<<NN/64, 256, 0, stream>>>(xb, Wt1, FIN, as1, ad1, gb, a_s, a_d);
  k_agg<<<NN/4, 256, 0, stream>>>(gb, col, offs, a_s, a_d, b1, ab);

  // GAT layer 2
  k_gemm_n<<<NN/64, 256, 0, stream>>>(ab, Wt2, HC, as2, ad2, gb, a_s, a_d);
  k_agg<<<NN/4, 256, 0, stream>>>(gb, col, offs, a_s, a_d, b2, ab);

  // encoder head
  k_gemm_big<<<dim3(HIDD/BNB, NSPLIT), 256, 0, stream>>>(ab, We, part);
  k_reduce<<<BB*HIDD/256, 256, 0, stream>>>(part, be, y);
  k_bn<<<HIDD, 64, 0, stream>>>(y, ybn);
  k_lnheads<<<BB, 512, 0, stream>>>(ybn, Wmu, bmu, Wvar, bvar, (float*)d_out);
}